// Round 11
// baseline (415.510 us; speedup 1.0000x reference)
//
#include <hip/hip_runtime.h>
#include <stdint.h>

typedef unsigned short u16;
typedef __attribute__((ext_vector_type(4))) float f32x4;
typedef __attribute__((ext_vector_type(16))) float f32x16;
typedef __attribute__((ext_vector_type(8))) short s16x8;
typedef __attribute__((ext_vector_type(8))) __bf16 bf16x8;
typedef __attribute__((ext_vector_type(8))) unsigned short u16x8;
typedef __attribute__((ext_vector_type(4))) unsigned short u16x4;
typedef __attribute__((ext_vector_type(4))) uint32_t u32x4;
typedef __attribute__((ext_vector_type(2))) uint32_t u32x2;

__device__ __forceinline__ f32x4 mfma16(s16x8 a, s16x8 b, f32x4 c) {
  return __builtin_amdgcn_mfma_f32_16x16x32_bf16(
      __builtin_bit_cast(bf16x8, a), __builtin_bit_cast(bf16x8, b), c, 0, 0, 0);
}
__device__ __forceinline__ f32x16 mfma32(s16x8 a, s16x8 b, f32x16 c) {
  return __builtin_amdgcn_mfma_f32_32x32x16_bf16(
      __builtin_bit_cast(bf16x8, a), __builtin_bit_cast(bf16x8, b), c, 0, 0, 0);
}

__device__ __forceinline__ void gl_lds16(const u16* g, u16* l) {
  __builtin_amdgcn_global_load_lds(
      (const __attribute__((address_space(1))) void*)g,
      (__attribute__((address_space(3))) void*)l, 16, 0, 0);
}

__device__ __forceinline__ u16 bf16rne(float f) {
  uint32_t u = __builtin_bit_cast(uint32_t, f);
  u += 0x7fffu + ((u >> 16) & 1u);
  return (u16)(u >> 16);
}

// ------- prologue: cast W (no pre-scale now) + lambda — one small launch -------
// blocks [0,6144): W -> Wt[768][2048] bf16; block 6144: lambda scalar.
__global__ void pre_kernel(const float* __restrict__ WQ, const float* __restrict__ WK,
                           const float* __restrict__ WV,
                           const float* __restrict__ lq1, const float* __restrict__ lq2,
                           const float* __restrict__ lk1, const float* __restrict__ lk2,
                           u16* __restrict__ Wt, float* __restrict__ lamp) {
  const int blk = blockIdx.x, tid = threadIdx.x;
  if (blk < 6144) {
    int i = blk * 256 + tid;  // 768*2048 elements
    int r = i >> 11, k = i & 2047;
    int sel = r >> 8, c = r & 255;
    const float* W = (sel == 0) ? WQ : (sel == 1) ? WK : WV;
    Wt[i] = bf16rne(W[(size_t)k * 256 + c]);
  } else if (tid < 64) {
    int t = tid;
    float d1 = lq1[t] * lk1[t] + lq1[t + 64] * lk1[t + 64];
    float d2 = lq2[t] * lk2[t] + lq2[t + 64] * lk2[t + 64];
#pragma unroll
    for (int off = 32; off; off >>= 1) {
      d1 += __shfl_xor(d1, off);
      d2 += __shfl_xor(d2, off);
    }
    if (t == 0) *lamp = expf(d1) + expf(d2) + (0.8f - 0.6f * expf(-3.6f));
  }
}

// ---------------- QKV projection GEMM: [16384,2048] x [2048,768] ----------------
// Fused x-cast, DMA edition (the R8/R9 lesson: keep staging on global_load_lds,
// NOT registers). A-tile staged as raw f32 (16KB/tile, 8-chunk rows, swizzle
// cg = c^(row&7)); f32->bf16 happens at LDS-read in the compute phase via
// compiler-emitted v_cvt_pk_bf16_f32 (RNE == bf16rne, bit-identical). B stays
// bf16 via gl_lds16. Single-barrier dbuf (R6/R10-proven). qscale applied to
// the Q accumulators in the epilogue (f32). LDS 48KB -> 3 blocks/CU (= grid cap).
__global__ __launch_bounds__(256) void proj_gemm(const float* __restrict__ x, const u16* __restrict__ Wt,
                                                 u16* __restrict__ Qb, u16* __restrict__ Kb,
                                                 u16* __restrict__ Vt, float qscale) {
  const int bid = blockIdx.x;             // 768 blocks
  const int xcd = bid & 7, j = bid >> 3;  // j in 0..95
  const int m0 = (xcd * 16 + (j / 6)) * 128;
  const int n0 = (j % 6) * 128;
  const int tid = threadIdx.x, lane = tid & 63, w = tid >> 6;
  const int ln = lane & 15, quad = lane >> 4;
  const int wm = w & 1, wn = w >> 1;
  __shared__ __align__(16) float Af[2][128 * 32];  // 2 x 16KB f32 A tiles
  __shared__ __align__(16) u16 Bs[2][128 * 32];    // 2 x 8KB bf16 B tiles
  f32x4 acc[4][4];
#pragma unroll
  for (int i = 0; i < 4; ++i)
#pragma unroll
    for (int jj = 0; jj < 4; ++jj) acc[i][jj] = f32x4{0.f, 0.f, 0.f, 0.f};

  auto stage = [&](int kk, int bi) {
    // A: 128 rows x 32 f32 = 1024 x 16B chunks; 4 per thread. cg = c^(row&7).
#pragma unroll
    for (int i = 0; i < 4; ++i) {
      int p = tid + i * 256;
      int row = p >> 3, c = p & 7;
      int cg = c ^ (row & 7);
      gl_lds16((const u16*)(x + (size_t)(m0 + row) * 2048 + kk + cg * 4),
               (u16*)(Af[bi] + (size_t)(p - lane) * 4));
    }
    // B: 128 rows x 32 bf16 = 512 x 16B chunks; 2 per thread. cg = (p&3)^(row&3).
#pragma unroll
    for (int i = 0; i < 2; ++i) {
      int p = tid + i * 256;
      int row = p >> 2, cg = (p & 3) ^ (row & 3);
      gl_lds16(Wt + (size_t)(n0 + row) * 2048 + kk + cg * 8, Bs[bi] + (size_t)(p - lane) * 8);
    }
  };

  stage(0, 0);
  for (int t = 0; t < 64; ++t) {
    __syncthreads();  // stage(t) complete (vmcnt drain); compute(t-1) reads done
    if (t + 1 < 64) stage((t + 1) * 32, (t + 1) & 1);
    const float* Afb = Af[t & 1];
    const u16* Bsb = Bs[t & 1];
    // A frags: row r, f32 chunks 2q and 2q+1 stored at (2q)^e, (2q+1)^e (e=r&7);
    // cvt to bf16 in-register (RNE, == pre-cast path bit-for-bit).
    s16x8 a[4];
#pragma unroll
    for (int mt = 0; mt < 4; ++mt) {
      int r = wm * 64 + mt * 16 + ln;
      int e = r & 7;
      f32x4 lo = *(const f32x4*)(Afb + r * 32 + (((2 * quad) ^ e) * 4));
      f32x4 hi = *(const f32x4*)(Afb + r * 32 + (((2 * quad + 1) ^ e) * 4));
      u16x8 o;
#pragma unroll
      for (int jj = 0; jj < 4; ++jj) {
        o[jj] = __builtin_bit_cast(u16, (__bf16)lo[jj]);
        o[4 + jj] = __builtin_bit_cast(u16, (__bf16)hi[jj]);
      }
      a[mt] = __builtin_bit_cast(s16x8, o);
    }
#pragma unroll
    for (int nt = 0; nt < 4; ++nt) {
      int r = wn * 64 + nt * 16 + ln;
      s16x8 bf = *(const s16x8*)(Bsb + r * 32 + ((quad ^ (r & 3)) * 8));
#pragma unroll
      for (int mt = 0; mt < 4; ++mt) acc[mt][nt] = mfma16(a[mt], bf, acc[mt][nt]);
    }
  }
#pragma unroll
  for (int mt = 0; mt < 4; ++mt)
#pragma unroll
    for (int nt = 0; nt < 4; ++nt) {
      int row0 = m0 + wm * 64 + mt * 16 + quad * 4;
      int col = n0 + wn * 64 + nt * 16 + ln;
      int sel = col >> 8, c = col & 255;
      float sc = (sel == 0) ? qscale : 1.f;  // Q pre-scale (scale*log2e), f32
      u16x4 vv;
#pragma unroll
      for (int jj = 0; jj < 4; ++jj) vv[jj] = bf16rne(acc[mt][nt][jj] * sc);
      if (sel == 2) {
        int b = row0 >> 12, s = row0 & 4095;
        *(u16x4*)(Vt + (size_t)b * 1048576 + (size_t)c * 4096 + s) = vv;
      } else {
        u16* dst = (sel == 0) ? Qb : Kb;
#pragma unroll
        for (int jj = 0; jj < 4; ++jj) dst[(size_t)(row0 + jj) * 256 + c] = vv[jj];
      }
    }
}

// ------- fused flash attention: 64 q-rows/block, 8 waves, dbuf staging -------
// R5/R6/R10-proven: ~124 us, MfmaUtil 38, no spills. Unchanged this round.
__global__ __launch_bounds__(512, 2) void attn_kernel(const u16* __restrict__ Qb,
                                                      const u16* __restrict__ Kb,
                                                      const u16* __restrict__ Vt,
                                                      const float* __restrict__ lamp,
                                                      float* __restrict__ out) {
  const int bid = blockIdx.x;
  const int xcd = bid & 7;
  const int b = xcd >> 1;
  const int qt = ((bid >> 3) << 1) + (xcd & 1);  // 0..63, q rows qt*64..+64
  const int tid = threadIdx.x, lane = tid & 63, w = tid >> 6;
  const int l5 = lane & 31, lh = lane >> 5;
  const int m = w & 1, kt = (w >> 1) & 1, qh = w >> 2;

  // dbuf: two 64KB buffers [Ks 32KB | Vs 32KB]; epilogue overlays the lot.
  __shared__ __align__(16) char smem[134144];
  float* buf0 = (float*)smem;            // epilogue: map0 O^T [256][65]
  float* buf1 = (float*)(smem + 66560);  // epilogue: map1 O^T [256][65]
  float* ls = (float*)(smem + 133120);   // l partials [w][32]

  const u16* Kg0 = Kb + ((size_t)b * 4096) * 256;
  const u16* Vg0 = Vt + (size_t)b * 1048576;

  auto stage = [&](int kb, char* base) {
    u16* Ks = (u16*)base;
    u16* Vs = (u16*)(base + 32768);
#pragma unroll
    for (int i = 0; i < 4; ++i) {
      int p = tid + i * 512;
      int row = p >> 5, c = p & 31;
      int cg = (c & 16) | ((c ^ row) & 15);
      gl_lds16(Kg0 + (size_t)(kb + row) * 256 + cg * 8, Ks + (size_t)(p - lane) * 8);
    }
#pragma unroll
    for (int i = 0; i < 4; ++i) {
      int p = tid + i * 512;
      int row = p >> 3, c = p & 7;
      int cg = c ^ (row & 7);
      gl_lds16(Vg0 + (size_t)row * 4096 + kb + cg * 8, Vs + (size_t)(p - lane) * 8);
    }
  };

  // kick off tile 0 staging before anything else
  stage(0, smem);

  // Q^T B-frags: B[k=d][n=q]: lane q = l5 within slice qh, d = s*16 + lh*8 + j
  s16x8 bq[8];
  {
    const u16* qp =
        Qb + ((size_t)(b * 4096 + qt * 64 + qh * 32 + l5)) * 256 + m * 128 + lh * 8;
#pragma unroll
    for (int s = 0; s < 8; ++s) bq[s] = *(const s16x8*)(qp + s * 16);
  }

  f32x16 O[8];
#pragma unroll
  for (int ct = 0; ct < 8; ++ct)
#pragma unroll
    for (int r = 0; r < 16; ++r) O[ct][r] = 0.f;
  float l_run = 0.f;

  for (int t = 0; t < 64; ++t) {
    __syncthreads();  // stage(t) complete (vmcnt drain); compute(t-1) reads done
    if (t + 1 < 64) stage((t + 1) * 64, smem + ((t + 1) & 1) * 65536);

    char* base = smem + (t & 1) * 65536;
    u16* Ks = (u16*)base;
    u16* Vs = (u16*)(base + 32768);

    // S^T[32 keys][32 q] = K . Q^T for (map m, keys kt*32..+32); two chains
    f32x16 Sa, Sb;
#pragma unroll
    for (int r = 0; r < 16; ++r) { Sa[r] = 0.f; Sb[r] = 0.f; }
#pragma unroll
    for (int s = 0; s < 8; s += 2) {
      int row = kt * 32 + l5;
      int c0 = m * 16 + s * 2 + lh;
      int c1 = m * 16 + (s + 1) * 2 + lh;
      s16x8 a0 = *(const s16x8*)(Ks + row * 256 + (((c0 & 16) | ((c0 ^ row) & 15))) * 8);
      s16x8 a1 = *(const s16x8*)(Ks + row * 256 + (((c1 & 16) | ((c1 ^ row) & 15))) * 8);
      Sa = mfma32(a0, bq[s], Sa);
      Sb = mfma32(a1, bq[s + 1], Sb);
    }

    // pre-read all V frags into regs (PV becomes pure-reg; hides LDS latency)
    s16x8 vfr0[8], vfr1[8];
#pragma unroll
    for (int ct = 0; ct < 8; ++ct) {
      int row = ct * 32 + l5;
      int c0v = (kt * 32) / 8 + lh;
      int c1v = (kt * 32 + 16) / 8 + lh;
      vfr0[ct] = *(const s16x8*)(Vs + row * 64 + ((c0v ^ (row & 7)) * 8));
      vfr1[ct] = *(const s16x8*)(Vs + row * 64 + ((c1v ^ (row & 7)) * 8));
    }

    // p = exp2(s) via raw v_exp_f32; accumulate l; pack to dwords (bf16rne)
    uint32_t P[8];
#pragma unroll
    for (int d = 0; d < 8; ++d) {
      float p0 = __builtin_amdgcn_exp2f(Sa[2 * d] + Sb[2 * d]);
      float p1 = __builtin_amdgcn_exp2f(Sa[2 * d + 1] + Sb[2 * d + 1]);
      l_run += p0 + p1;
      P[d] = (uint32_t)bf16rne(p0) | ((uint32_t)bf16rne(p1) << 16);
    }

    // PV: O^T[256 vcol][32 q] += V^T . P^T ; half-exchange via permlane32_swap:
    // swap(P[4k],P[4k+2]) -> (fd0,fd2), swap(P[4k+1],P[4k+3]) -> (fd1,fd3)
#pragma unroll
    for (int ks = 0; ks < 2; ++ks) {
      u32x2 s02 = __builtin_amdgcn_permlane32_swap(P[ks * 4 + 0], P[ks * 4 + 2], false, false);
      u32x2 s13 = __builtin_amdgcn_permlane32_swap(P[ks * 4 + 1], P[ks * 4 + 3], false, false);
      u32x4 fd;
      fd[0] = s02[0]; fd[1] = s13[0]; fd[2] = s02[1]; fd[3] = s13[1];
      s16x8 pf = __builtin_bit_cast(s16x8, fd);
      if (ks == 0) {
#pragma unroll
        for (int ct = 0; ct < 8; ++ct) O[ct] = mfma32(vfr0[ct], pf, O[ct]);
      } else {
#pragma unroll
        for (int ct = 0; ct < 8; ++ct) O[ct] = mfma32(vfr1[ct], pf, O[ct]);
      }
    }
  }

  // ---------------- epilogue ----------------
  float lam = *lamp;
  l_run += __shfl_xor(l_run, 32);  // fold lh (partner holds other 16 keys)
  __syncthreads();                 // B1: loop reads done; smem becomes buf0/buf1/ls
  if (lane < 32) ls[w * 32 + l5] = l_run;
  float* bufm = m ? buf1 : buf0;
  const int qb0 = qh * 32;
  if (kt == 1) {
#pragma unroll
    for (int ct = 0; ct < 8; ++ct)
#pragma unroll
      for (int r = 0; r < 16; ++r) {
        int vcol = ct * 32 + (r & 3) + 8 * (r >> 2) + 4 * lh;
        bufm[vcol * 65 + qb0 + l5] = O[ct][r];
      }
  }
  __syncthreads();  // B2
  if (kt == 0) {
    float linv = 1.f / (ls[w * 32 + l5] + ls[(w | 2) * 32 + l5]);
#pragma unroll
    for (int ct = 0; ct < 8; ++ct)
#pragma unroll
      for (int r = 0; r < 16; ++r) {
        int vcol = ct * 32 + (r & 3) + 8 * (r >> 2) + 4 * lh;
        bufm[vcol * 65 + qb0 + l5] = (O[ct][r] + bufm[vcol * 65 + qb0 + l5]) * linv;
      }
  }
  __syncthreads();  // B3
  // cooperative write: out[q][col], coalesced; 512 threads = 2 q-halves x 256 cols
  float* og = out + ((size_t)(b * 4096 + qt * 64)) * 256;
  const int col = tid & 255, half = tid >> 8;
#pragma unroll
  for (int j2 = 0; j2 < 32; ++j2) {
    int q = half * 32 + j2;
    float v = buf0[col * 65 + q] - lam * buf1[col * 65 + q];
    og[(size_t)q * 256 + col] = v;
  }
}

extern "C" void kernel_launch(void* const* d_in, const int* in_sizes, int n_in,
                              void* d_out, int out_size, void* d_ws, size_t ws_size,
                              hipStream_t stream) {
  (void)in_sizes; (void)n_in; (void)out_size; (void)ws_size;
  const float* x   = (const float*)d_in[0];
  const float* WQ  = (const float*)d_in[1];
  const float* WK  = (const float*)d_in[2];
  const float* WV  = (const float*)d_in[3];
  const float* lq1 = (const float*)d_in[4];
  const float* lq2 = (const float*)d_in[5];
  const float* lk1 = (const float*)d_in[6];
  const float* lk2 = (const float*)d_in[7];
  float* out = (float*)d_out;

  char* ws = (char*)d_ws;
  u16* Wt = (u16*)ws;   ws += (size_t)768 * 2048 * 2;
  u16* Qb = (u16*)ws;   ws += (size_t)16384 * 256 * 2;
  u16* Kb = (u16*)ws;   ws += (size_t)16384 * 256 * 2;
  u16* Vt = (u16*)ws;   ws += (size_t)16384 * 256 * 2;  // [b][col 256][s 4096]
  float* lamp = (float*)ws;

  const float qscale = 0.0883883476f * 1.44269504f;  // HEAD_DIM^-0.5 * log2(e)

  hipLaunchKernelGGL(pre_kernel, dim3(6145), dim3(256), 0, stream,
                     WQ, WK, WV, lq1, lq2, lk1, lk2, Wt, lamp);
  hipLaunchKernelGGL(proj_gemm, dim3(768), dim3(256), 0, stream, x, Wt, Qb, Kb, Vt, qscale);
  hipLaunchKernelGGL(attn_kernel, dim3(256), dim3(512), 0, stream, Qb, Kb, Vt, lamp, out);
}

// Round 12
// 396.249 us; speedup vs baseline: 1.0486x; 1.0486x over previous
//
#include <hip/hip_runtime.h>
#include <stdint.h>

typedef unsigned short u16;
typedef __attribute__((ext_vector_type(4))) float f32x4;
typedef __attribute__((ext_vector_type(16))) float f32x16;
typedef __attribute__((ext_vector_type(8))) short s16x8;
typedef __attribute__((ext_vector_type(8))) __bf16 bf16x8;
typedef __attribute__((ext_vector_type(8))) unsigned short u16x8;
typedef __attribute__((ext_vector_type(4))) unsigned short u16x4;
typedef __attribute__((ext_vector_type(4))) uint32_t u32x4;
typedef __attribute__((ext_vector_type(2))) uint32_t u32x2;

__device__ __forceinline__ f32x4 mfma16(s16x8 a, s16x8 b, f32x4 c) {
  return __builtin_amdgcn_mfma_f32_16x16x32_bf16(
      __builtin_bit_cast(bf16x8, a), __builtin_bit_cast(bf16x8, b), c, 0, 0, 0);
}
__device__ __forceinline__ f32x16 mfma32(s16x8 a, s16x8 b, f32x16 c) {
  return __builtin_amdgcn_mfma_f32_32x32x16_bf16(
      __builtin_bit_cast(bf16x8, a), __builtin_bit_cast(bf16x8, b), c, 0, 0, 0);
}

__device__ __forceinline__ void gl_lds16(const u16* g, u16* l) {
  __builtin_amdgcn_global_load_lds(
      (const __attribute__((address_space(1))) void*)g,
      (__attribute__((address_space(3))) void*)l, 16, 0, 0);
}

__device__ __forceinline__ u16 bf16rne(float f) {
  uint32_t u = __builtin_bit_cast(uint32_t, f);
  u += 0x7fffu + ((u >> 16) & 1u);
  return (u16)(u >> 16);
}

// ------- merged prologue: cast x, cast W (+qscale), lambda — one launch -------
// (R10-proven.) blocks [0,16384): x -> xb bf16; [16384,22528): W -> Wt;
// block 22528: lambda scalar.
__global__ void pre_kernel(const float* __restrict__ x, const float* __restrict__ WQ,
                           const float* __restrict__ WK, const float* __restrict__ WV,
                           const float* __restrict__ lq1, const float* __restrict__ lq2,
                           const float* __restrict__ lk1, const float* __restrict__ lk2,
                           u16* __restrict__ xb, u16* __restrict__ Wt,
                           float* __restrict__ lamp, float qscale) {
  const int blk = blockIdx.x, tid = threadIdx.x;
  if (blk < 16384) {
    size_t i = ((size_t)blk * 256 + tid) * 8;
    f32x4 a = *(const f32x4*)(x + i);
    f32x4 b = *(const f32x4*)(x + i + 4);
    u16x8 o;
#pragma unroll
    for (int j = 0; j < 4; ++j) { o[j] = bf16rne(a[j]); o[4 + j] = bf16rne(b[j]); }
    *(u16x8*)(xb + i) = o;
  } else if (blk < 22528) {
    int i = (blk - 16384) * 256 + tid;  // 768*2048 elements
    int r = i >> 11, k = i & 2047;
    int sel = r >> 8, c = r & 255;
    const float* W = (sel == 0) ? WQ : (sel == 1) ? WK : WV;
    float v = W[(size_t)k * 256 + c];
    if (sel == 0) v *= qscale;
    Wt[i] = bf16rne(v);
  } else {
    if (tid < 64) {
      int t = tid;
      float d1 = lq1[t] * lk1[t] + lq1[t + 64] * lk1[t + 64];
      float d2 = lq2[t] * lk2[t] + lq2[t + 64] * lk2[t + 64];
#pragma unroll
      for (int off = 32; off; off >>= 1) {
        d1 += __shfl_xor(d1, off);
        d2 += __shfl_xor(d2, off);
      }
      if (t == 0) *lamp = expf(d1) + expf(d2) + (0.8f - 0.6f * expf(-3.6f));
    }
  }
}

// ---------------- QKV projection GEMM: [16384,2048] x [2048,768] ----------------
// R10 inner loop (bf16 operands via global_load_lds — the only staging path
// that wins here; R8/R9/R11 all lost) + T3/T4 depth-2 counted-vmcnt pipeline:
// 3 LDS buffers; iter t: {vmcnt(4) [drains stage(t), keeps stage(t+1)'s 4 DMA
// ops in flight ACROSS the barrier] ; s_barrier ; issue stage(t+2) ; compute(t)}.
// Each stage now has ~2 iterations to cover HBM latency (the R10 depth-1 form
// gave it one compute phase -> per-iter stall, MfmaUtil 15%, ~82us).
// Hazards: buffers distinct mod 3; lgkmcnt(0)+barrier retire compute(t-1)'s
// ds_reads before stage(t+2) overwrites that buffer; t=62 skips issue, t=63
// peeled with vmcnt(0). Zero extra VGPRs (DMA path), no sched_barrier pinning.
__global__ __launch_bounds__(256) void proj_gemm(const u16* __restrict__ xb, const u16* __restrict__ Wt,
                                                 u16* __restrict__ Qb, u16* __restrict__ Kb,
                                                 u16* __restrict__ Vt) {
  const int bid = blockIdx.x;             // 768 blocks
  const int xcd = bid & 7, j = bid >> 3;  // j in 0..95
  const int m0 = (xcd * 16 + (j / 6)) * 128;
  const int n0 = (j % 6) * 128;
  const int tid = threadIdx.x, lane = tid & 63, w = tid >> 6;
  const int ln = lane & 15, quad = lane >> 4;
  const int wm = w & 1, wn = w >> 1;
  __shared__ __align__(16) u16 As[3][128 * 32];  // 3 x 8KB bf16 A tiles
  __shared__ __align__(16) u16 Bs[3][128 * 32];  // 3 x 8KB bf16 B tiles
  f32x4 acc[4][4];
#pragma unroll
  for (int i = 0; i < 4; ++i)
#pragma unroll
    for (int jj = 0; jj < 4; ++jj) acc[i][jj] = f32x4{0.f, 0.f, 0.f, 0.f};

  auto stage = [&](int kk, int bi) {
    // 4 gl_lds16 per thread per stage (2 A + 2 B) -> vmcnt formula N = 4 x depth-1.
#pragma unroll
    for (int i = 0; i < 2; ++i) {
      int p = tid + i * 256;
      int row = p >> 2, cg = (p & 3) ^ (row & 3);
      gl_lds16(xb + (size_t)(m0 + row) * 2048 + kk + cg * 8, As[bi] + (size_t)(p - lane) * 8);
      gl_lds16(Wt + (size_t)(n0 + row) * 2048 + kk + cg * 8, Bs[bi] + (size_t)(p - lane) * 8);
    }
  };
  auto computeTile = [&](int bi) {
    const u16* Asb = As[bi];
    const u16* Bsb = Bs[bi];
    s16x8 a[4];
#pragma unroll
    for (int mt = 0; mt < 4; ++mt) {
      int r = wm * 64 + mt * 16 + ln;
      a[mt] = *(const s16x8*)(Asb + r * 32 + ((quad ^ (r & 3)) * 8));
    }
#pragma unroll
    for (int nt = 0; nt < 4; ++nt) {
      int r = wn * 64 + nt * 16 + ln;
      s16x8 bf = *(const s16x8*)(Bsb + r * 32 + ((quad ^ (r & 3)) * 8));
#pragma unroll
      for (int mt = 0; mt < 4; ++mt) acc[mt][nt] = mfma16(a[mt], bf, acc[mt][nt]);
    }
  };

  // prologue: two tiles in flight
  stage(0, 0);
  stage(32, 1);

  for (int t = 0; t < 63; ++t) {
    asm volatile("s_waitcnt vmcnt(4) lgkmcnt(0)" ::: "memory");
    __builtin_amdgcn_s_barrier();
    if (t + 2 < 64) stage((t + 2) * 32, (t + 2) % 3);
    computeTile(t % 3);
  }
  // peeled final tile: drain everything (only stage(63) can remain in flight)
  asm volatile("s_waitcnt vmcnt(0) lgkmcnt(0)" ::: "memory");
  __builtin_amdgcn_s_barrier();
  computeTile(63 % 3);

#pragma unroll
  for (int mt = 0; mt < 4; ++mt)
#pragma unroll
    for (int nt = 0; nt < 4; ++nt) {
      int row0 = m0 + wm * 64 + mt * 16 + quad * 4;
      int col = n0 + wn * 64 + nt * 16 + ln;
      int sel = col >> 8, c = col & 255;
      u16x4 vv;
#pragma unroll
      for (int jj = 0; jj < 4; ++jj) vv[jj] = bf16rne(acc[mt][nt][jj]);
      if (sel == 2) {
        int b = row0 >> 12, s = row0 & 4095;
        *(u16x4*)(Vt + (size_t)b * 1048576 + (size_t)c * 4096 + s) = vv;
      } else {
        u16* dst = (sel == 0) ? Qb : Kb;
#pragma unroll
        for (int jj = 0; jj < 4; ++jj) dst[(size_t)(row0 + jj) * 256 + c] = vv[jj];
      }
    }
}

// ------- fused flash attention: 64 q-rows/block, 8 waves, dbuf staging -------
// R5/R6/R10-proven: ~124 us, MfmaUtil 38, no spills. Unchanged this round.
__global__ __launch_bounds__(512, 2) void attn_kernel(const u16* __restrict__ Qb,
                                                      const u16* __restrict__ Kb,
                                                      const u16* __restrict__ Vt,
                                                      const float* __restrict__ lamp,
                                                      float* __restrict__ out) {
  const int bid = blockIdx.x;
  const int xcd = bid & 7;
  const int b = xcd >> 1;
  const int qt = ((bid >> 3) << 1) + (xcd & 1);  // 0..63, q rows qt*64..+64
  const int tid = threadIdx.x, lane = tid & 63, w = tid >> 6;
  const int l5 = lane & 31, lh = lane >> 5;
  const int m = w & 1, kt = (w >> 1) & 1, qh = w >> 2;

  // dbuf: two 64KB buffers [Ks 32KB | Vs 32KB]; epilogue overlays the lot.
  __shared__ __align__(16) char smem[134144];
  float* buf0 = (float*)smem;            // epilogue: map0 O^T [256][65]
  float* buf1 = (float*)(smem + 66560);  // epilogue: map1 O^T [256][65]
  float* ls = (float*)(smem + 133120);   // l partials [w][32]

  const u16* Kg0 = Kb + ((size_t)b * 4096) * 256;
  const u16* Vg0 = Vt + (size_t)b * 1048576;

  auto stage = [&](int kb, char* base) {
    u16* Ks = (u16*)base;
    u16* Vs = (u16*)(base + 32768);
#pragma unroll
    for (int i = 0; i < 4; ++i) {
      int p = tid + i * 512;
      int row = p >> 5, c = p & 31;
      int cg = (c & 16) | ((c ^ row) & 15);
      gl_lds16(Kg0 + (size_t)(kb + row) * 256 + cg * 8, Ks + (size_t)(p - lane) * 8);
    }
#pragma unroll
    for (int i = 0; i < 4; ++i) {
      int p = tid + i * 512;
      int row = p >> 3, c = p & 7;
      int cg = c ^ (row & 7);
      gl_lds16(Vg0 + (size_t)row * 4096 + kb + cg * 8, Vs + (size_t)(p - lane) * 8);
    }
  };

  // kick off tile 0 staging before anything else
  stage(0, smem);

  // Q^T B-frags: B[k=d][n=q]: lane q = l5 within slice qh, d = s*16 + lh*8 + j
  s16x8 bq[8];
  {
    const u16* qp =
        Qb + ((size_t)(b * 4096 + qt * 64 + qh * 32 + l5)) * 256 + m * 128 + lh * 8;
#pragma unroll
    for (int s = 0; s < 8; ++s) bq[s] = *(const s16x8*)(qp + s * 16);
  }

  f32x16 O[8];
#pragma unroll
  for (int ct = 0; ct < 8; ++ct)
#pragma unroll
    for (int r = 0; r < 16; ++r) O[ct][r] = 0.f;
  float l_run = 0.f;

  for (int t = 0; t < 64; ++t) {
    __syncthreads();  // stage(t) complete (vmcnt drain); compute(t-1) reads done
    if (t + 1 < 64) stage((t + 1) * 64, smem + ((t + 1) & 1) * 65536);

    char* base = smem + (t & 1) * 65536;
    u16* Ks = (u16*)base;
    u16* Vs = (u16*)(base + 32768);

    // S^T[32 keys][32 q] = K . Q^T for (map m, keys kt*32..+32); two chains
    f32x16 Sa, Sb;
#pragma unroll
    for (int r = 0; r < 16; ++r) { Sa[r] = 0.f; Sb[r] = 0.f; }
#pragma unroll
    for (int s = 0; s < 8; s += 2) {
      int row = kt * 32 + l5;
      int c0 = m * 16 + s * 2 + lh;
      int c1 = m * 16 + (s + 1) * 2 + lh;
      s16x8 a0 = *(const s16x8*)(Ks + row * 256 + (((c0 & 16) | ((c0 ^ row) & 15))) * 8);
      s16x8 a1 = *(const s16x8*)(Ks + row * 256 + (((c1 & 16) | ((c1 ^ row) & 15))) * 8);
      Sa = mfma32(a0, bq[s], Sa);
      Sb = mfma32(a1, bq[s + 1], Sb);
    }

    // pre-read all V frags into regs (PV becomes pure-reg; hides LDS latency)
    s16x8 vfr0[8], vfr1[8];
#pragma unroll
    for (int ct = 0; ct < 8; ++ct) {
      int row = ct * 32 + l5;
      int c0v = (kt * 32) / 8 + lh;
      int c1v = (kt * 32 + 16) / 8 + lh;
      vfr0[ct] = *(const s16x8*)(Vs + row * 64 + ((c0v ^ (row & 7)) * 8));
      vfr1[ct] = *(const s16x8*)(Vs + row * 64 + ((c1v ^ (row & 7)) * 8));
    }

    // p = exp2(s) via raw v_exp_f32; accumulate l; pack to dwords (bf16rne)
    uint32_t P[8];
#pragma unroll
    for (int d = 0; d < 8; ++d) {
      float p0 = __builtin_amdgcn_exp2f(Sa[2 * d] + Sb[2 * d]);
      float p1 = __builtin_amdgcn_exp2f(Sa[2 * d + 1] + Sb[2 * d + 1]);
      l_run += p0 + p1;
      P[d] = (uint32_t)bf16rne(p0) | ((uint32_t)bf16rne(p1) << 16);
    }

    // PV: O^T[256 vcol][32 q] += V^T . P^T ; half-exchange via permlane32_swap:
    // swap(P[4k],P[4k+2]) -> (fd0,fd2), swap(P[4k+1],P[4k+3]) -> (fd1,fd3)
#pragma unroll
    for (int ks = 0; ks < 2; ++ks) {
      u32x2 s02 = __builtin_amdgcn_permlane32_swap(P[ks * 4 + 0], P[ks * 4 + 2], false, false);
      u32x2 s13 = __builtin_amdgcn_permlane32_swap(P[ks * 4 + 1], P[ks * 4 + 3], false, false);
      u32x4 fd;
      fd[0] = s02[0]; fd[1] = s13[0]; fd[2] = s02[1]; fd[3] = s13[1];
      s16x8 pf = __builtin_bit_cast(s16x8, fd);
      if (ks == 0) {
#pragma unroll
        for (int ct = 0; ct < 8; ++ct) O[ct] = mfma32(vfr0[ct], pf, O[ct]);
      } else {
#pragma unroll
        for (int ct = 0; ct < 8; ++ct) O[ct] = mfma32(vfr1[ct], pf, O[ct]);
      }
    }
  }

  // ---------------- epilogue ----------------
  float lam = *lamp;
  l_run += __shfl_xor(l_run, 32);  // fold lh (partner holds other 16 keys)
  __syncthreads();                 // B1: loop reads done; smem becomes buf0/buf1/ls
  if (lane < 32) ls[w * 32 + l5] = l_run;
  float* bufm = m ? buf1 : buf0;
  const int qb0 = qh * 32;
  if (kt == 1) {
#pragma unroll
    for (int ct = 0; ct < 8; ++ct)
#pragma unroll
      for (int r = 0; r < 16; ++r) {
        int vcol = ct * 32 + (r & 3) + 8 * (r >> 2) + 4 * lh;
        bufm[vcol * 65 + qb0 + l5] = O[ct][r];
      }
  }
  __syncthreads();  // B2
  if (kt == 0) {
    float linv = 1.f / (ls[w * 32 + l5] + ls[(w | 2) * 32 + l5]);
#pragma unroll
    for (int ct = 0; ct < 8; ++ct)
#pragma unroll
      for (int r = 0; r < 16; ++r) {
        int vcol = ct * 32 + (r & 3) + 8 * (r >> 2) + 4 * lh;
        bufm[vcol * 65 + qb0 + l5] = (O[ct][r] + bufm[vcol * 65 + qb0 + l5]) * linv;
      }
  }
  __syncthreads();  // B3
  // cooperative write: out[q][col], coalesced; 512 threads = 2 q-halves x 256 cols
  float* og = out + ((size_t)(b * 4096 + qt * 64)) * 256;
  const int col = tid & 255, half = tid >> 8;
#pragma unroll
  for (int j2 = 0; j2 < 32; ++j2) {
    int q = half * 32 + j2;
    float v = buf0[col * 65 + q] - lam * buf1[col * 65 + q];
    og[(size_t)q * 256 + col] = v;
  }
}

extern "C" void kernel_launch(void* const* d_in, const int* in_sizes, int n_in,
                              void* d_out, int out_size, void* d_ws, size_t ws_size,
                              hipStream_t stream) {
  (void)in_sizes; (void)n_in; (void)out_size; (void)ws_size;
  const float* x   = (const float*)d_in[0];
  const float* WQ  = (const float*)d_in[1];
  const float* WK  = (const float*)d_in[2];
  const float* WV  = (const float*)d_in[3];
  const float* lq1 = (const float*)d_in[4];
  const float* lq2 = (const float*)d_in[5];
  const float* lk1 = (const float*)d_in[6];
  const float* lk2 = (const float*)d_in[7];
  float* out = (float*)d_out;

  char* ws = (char*)d_ws;
  u16* xb = (u16*)ws;   ws += (size_t)16384 * 2048 * 2;
  u16* Wt = (u16*)ws;   ws += (size_t)768 * 2048 * 2;
  u16* Qb = (u16*)ws;   ws += (size_t)16384 * 256 * 2;
  u16* Kb = (u16*)ws;   ws += (size_t)16384 * 256 * 2;
  u16* Vt = (u16*)ws;   ws += (size_t)16384 * 256 * 2;  // [b][col 256][s 4096]
  float* lamp = (float*)ws;

  const float qscale = 0.0883883476f * 1.44269504f;  // HEAD_DIM^-0.5 * log2(e)

  hipLaunchKernelGGL(pre_kernel, dim3(22529), dim3(256), 0, stream,
                     x, WQ, WK, WV, lq1, lq2, lk1, lk2, xb, Wt, lamp, qscale);
  hipLaunchKernelGGL(proj_gemm, dim3(768), dim3(256), 0, stream, xb, Wt, Qb, Kb, Vt);
  hipLaunchKernelGGL(attn_kernel, dim3(256), dim3(512), 0, stream, Qb, Kb, Vt, lamp, out);
}